// Round 3
// baseline (1125.222 us; speedup 1.0000x reference)
//
#include <hip/hip_runtime.h>

#define T_STEPS 512
#define BATCH   512
#define HID     64
#define NGATES  256   // 4*HID
#define CH      64    // steps per chunk (xg staged in LDS per chunk)

// Keep a value pinned in a VGPR at this point (best-effort).
#define PIN(x) asm volatile("" : "+v"(x))

__device__ __forceinline__ float fast_sigmoid(float x) {
    return 1.0f / (1.0f + __expf(-x));
}
__device__ __forceinline__ float fast_tanh(float x) {
    // tanh(x) = 1 - 2/(1+e^{2x}); saturates correctly, no NaN.
    return 1.0f - 2.0f / (1.0f + __expf(2.0f * x));
}

// One block per batch row, 256 threads (thread g owns gate g), 2 blocks/CU.
// Per 64-step chunk: bulk-GEMM the x-contribution into LDS (latency-tolerant,
// x row read via wave-uniform scalar loads), then run the serial recurrence
// with ONLY the 64-wide h-dot inside (weights comfortably register-resident).
template<int K_IN, bool LAST>
__global__ __launch_bounds__(256, 2)
void lstm_layer(const float* __restrict__ xin,   // [B,T,K_IN]
                const float* __restrict__ W_ih,  // [256,K_IN]
                const float* __restrict__ W_hh,  // [256,64]
                const float* __restrict__ b_ih,  // [256]
                const float* __restrict__ b_hh,  // [256]
                float* __restrict__ hout,        // [B,T,64] (only if !LAST)
                const float* __restrict__ W_fc,  // [1,64]   (only if LAST)
                const float* __restrict__ b_fc,  // [1]      (only if LAST)
                float* __restrict__ fcout)       // [B]      (only if LAST)
{
    __shared__ __align__(16) float xg_s[CH * NGATES];  // 64 KB
    __shared__ __align__(16) float gates_s[NGATES];
    __shared__ __align__(16) float hbuf[HID];

    const int b    = blockIdx.x;
    const int g    = threadIdx.x;
    const int lane = g & 63;

    // Persistent across the whole kernel: this gate's recurrent weight row.
    float4 whh4[HID / 4];
    {
        const float4* hr = reinterpret_cast<const float4*>(W_hh + (size_t)g * HID);
        #pragma unroll
        for (int k = 0; k < HID / 4; ++k) whh4[k] = hr[k];
        #pragma unroll
        for (int k = 0; k < HID / 4; ++k) {
            PIN(whh4[k].x); PIN(whh4[k].y); PIN(whh4[k].z); PIN(whh4[k].w);
        }
    }
    const float bias = b_ih[g] + b_hh[g];

    if (g < HID) hbuf[g] = 0.0f;
    float c = 0.0f;
    __syncthreads();

    for (int c0 = 0; c0 < T_STEPS; c0 += CH) {
        // ---- Chunk GEMM: xg_s[tm][g] = bias + dot(W_ih[g], x[b][c0+tm]) ----
        // Safe vs previous chunk: every thread passed the last step's bar2.
        {
            // Transient W_ih row (live only in this phase).
            float4 wih4[K_IN / 4];
            const float4* wr = reinterpret_cast<const float4*>(W_ih + (size_t)g * K_IN);
            #pragma unroll
            for (int k = 0; k < K_IN / 4; ++k) wih4[k] = wr[k];

            // Wave-uniform x row pointer -> scalar (SGPR) loads, no LDS/VMEM tax.
            const float* xrow = xin + ((size_t)b * T_STEPS + c0) * K_IN;
            for (int tm = 0; tm < CH; ++tm) {
                float a0 = bias, a1 = 0.0f, a2 = 0.0f, a3 = 0.0f;
                const float* xp = xrow + tm * K_IN;
                #pragma unroll
                for (int k = 0; k < K_IN / 4; ++k) {
                    a0 = fmaf(wih4[k].x, xp[4 * k + 0], a0);
                    a1 = fmaf(wih4[k].y, xp[4 * k + 1], a1);
                    a2 = fmaf(wih4[k].z, xp[4 * k + 2], a2);
                    a3 = fmaf(wih4[k].w, xp[4 * k + 3], a3);
                }
                xg_s[tm * NGATES + g] = (a0 + a1) + (a2 + a3);  // lanes consecutive: conflict-free
            }
        }
        __syncthreads();  // xg_s ready

        // ---- Serial recurrence: only the h-dot remains ----
        for (int tm = 0; tm < CH; ++tm) {
            const float4* hb4 = reinterpret_cast<const float4*>(hbuf);
            float a0 = xg_s[tm * NGATES + g], a1 = 0.0f, a2 = 0.0f, a3 = 0.0f;
            #pragma unroll
            for (int k = 0; k < HID / 4; ++k) {
                float4 hv = hb4[k];                 // broadcast b128 reads
                a0 = fmaf(whh4[k].x, hv.x, a0);
                a1 = fmaf(whh4[k].y, hv.y, a1);
                a2 = fmaf(whh4[k].z, hv.z, a2);
                a3 = fmaf(whh4[k].w, hv.w, a3);
            }
            float acc = (a0 + a1) + (a2 + a3);

            // Wave 2 (threads 128..191) is exactly the tanh 'g' gate: uniform branch.
            float a = ((g >> 6) == 2) ? fast_tanh(acc) : fast_sigmoid(acc);
            gates_s[g] = a;
            __syncthreads();   // bar1: gates visible

            // Redundant c/h update in all 4 waves (no idle-wave phase).
            float i_ = gates_s[lane];
            float f_ = gates_s[HID + lane];
            float g_ = gates_s[2 * HID + lane];
            float o_ = gates_s[3 * HID + lane];
            c = fmaf(f_, c, i_ * g_);
            float h = o_ * fast_tanh(c);
            if (g < HID) {
                hbuf[g] = h;
                if (!LAST) hout[((size_t)b * T_STEPS + (c0 + tm)) * HID + g] = h;
            }
            __syncthreads();   // bar2: hbuf ready for next step, gates_s reusable
        }
    }

    if (LAST) {
        // FC: out[b] = dot(W_fc, h_last) + b_fc (threads 0..63 = wave 0).
        if (g < HID) {
            float v = hbuf[g] * W_fc[g];
            #pragma unroll
            for (int off = 32; off; off >>= 1) v += __shfl_down(v, off);
            if (g == 0) fcout[b] = v + b_fc[0];
        }
    }
}

extern "C" void kernel_launch(void* const* d_in, const int* in_sizes, int n_in,
                              void* d_out, int out_size, void* d_ws, size_t ws_size,
                              hipStream_t stream) {
    const float* x     = (const float*)d_in[0];
    const float* W_ih0 = (const float*)d_in[1];
    const float* W_hh0 = (const float*)d_in[2];
    const float* b_ih0 = (const float*)d_in[3];
    const float* b_hh0 = (const float*)d_in[4];
    const float* W_ih1 = (const float*)d_in[5];
    const float* W_hh1 = (const float*)d_in[6];
    const float* b_ih1 = (const float*)d_in[7];
    const float* b_hh1 = (const float*)d_in[8];
    const float* W_fc  = (const float*)d_in[9];
    const float* b_fc  = (const float*)d_in[10];

    float* out = (float*)d_out;
    float* h1  = (float*)d_ws;   // [512,512,64] f32 = 64 MB scratch

    lstm_layer<32, false><<<BATCH, 256, 0, stream>>>(
        x, W_ih0, W_hh0, b_ih0, b_hh0, h1, nullptr, nullptr, nullptr);
    lstm_layer<64, true><<<BATCH, 256, 0, stream>>>(
        h1, W_ih1, W_hh1, b_ih1, b_hh1, nullptr, W_fc, b_fc, out);
}

// Round 4
// 960.173 us; speedup vs baseline: 1.1719x; 1.1719x over previous
//
#include <hip/hip_runtime.h>

#define T_STEPS 512
#define BATCH   512
#define HID     64
#define NGATES  256   // 4*HID
#define CH      32    // steps per chunk (xg staged in LDS per chunk)

#define PIN(x) asm volatile("" : "+v"(x))

__device__ __forceinline__ float fast_tanh(float x) {
    // tanh(x) = 1 - 2/(1+e^{2x}); saturates correctly, no NaN.
    return 1.0f - 2.0f / (1.0f + __expf(2.0f * x));
}

// One block per batch row, 256 threads, 2 blocks/CU.
// Thread mapping (serial phase): wave w = tid>>6, lane l = tid&63.
//   gid = l>>4 (gate i,f,g,o), u = w*16 + (l&15) (hidden unit), gate row
//   gr = gid*64 + u. The 4 gates of unit u sit in ONE wave at lanes
//   l, l^16, l^32, l^48 -> gate exchange is 3 intra-wave shuffles, and the
//   step needs only ONE barrier (hbuf is parity double-buffered).
template<int K_IN, bool LAST>
__global__ __launch_bounds__(256, 2)
void lstm_layer(const float* __restrict__ xin,   // [B,T,K_IN]
                const float* __restrict__ W_ih,  // [256,K_IN]
                const float* __restrict__ W_hh,  // [256,64]
                const float* __restrict__ b_ih,  // [256]
                const float* __restrict__ b_hh,  // [256]
                float* __restrict__ hout,        // [B,T,64] (if !LAST)
                const float* __restrict__ W_fc,  // [1,64]   (if LAST)
                const float* __restrict__ b_fc,  // [1]      (if LAST)
                float* __restrict__ fcout)       // [B]      (if LAST)
{
    __shared__ __align__(16) float xg_s[CH * NGATES];   // 32 KB
    __shared__ __align__(16) float xstage[CH * K_IN];   // 4 or 8 KB
    __shared__ __align__(16) float hbuf[2][HID];

    const int b   = blockIdx.x;
    const int tid = threadIdx.x;
    const int w   = tid >> 6;
    const int l   = tid & 63;
    const int gid = l >> 4;               // 0=i 1=f 2=g 3=o
    const int u   = (w << 4) + (l & 15);  // hidden unit
    const int gr  = (gid << 6) + u;       // gate row

    // Branchless activation: act(x) = sB + sC/(1+exp(sA*x)).
    //   sigmoid: sA=-1 sB=0 sC=1 ; tanh: sA=2 sB=1 sC=-2
    const bool istanh = (gid == 2);
    const float sA = istanh ? 2.0f : -1.0f;
    const float sB = istanh ? 1.0f : 0.0f;
    const float sC = istanh ? -2.0f : 1.0f;

    // Persistent recurrent weight row (64 floats).
    float4 whh4[HID / 4];
    {
        const float4* hr = reinterpret_cast<const float4*>(W_hh + (size_t)gr * HID);
        #pragma unroll
        for (int k = 0; k < HID / 4; ++k) whh4[k] = hr[k];
        #pragma unroll
        for (int k = 0; k < HID / 4; ++k) {
            PIN(whh4[k].x); PIN(whh4[k].y); PIN(whh4[k].z); PIN(whh4[k].w);
        }
    }
    const float bias = b_ih[gr] + b_hh[gr];

    if (tid < 128) hbuf[tid >> 6][tid & 63] = 0.0f;
    float c = 0.0f;
    __syncthreads();

    const float* xrow = xin + (size_t)b * T_STEPS * K_IN;

    for (int c0 = 0; c0 < T_STEPS; c0 += CH) {
        // ---- Stage x chunk into LDS (coalesced float4) ----
        {
            const float4* src = reinterpret_cast<const float4*>(xrow + c0 * K_IN);
            float4* dst = reinterpret_cast<float4*>(xstage);
            #pragma unroll
            for (int i = tid; i < CH * K_IN / 4; i += 256) dst[i] = src[i];
        }
        // W_ih row: short live range, reloaded per chunk (L2-resident, 64 KB matrix).
        float4 wih4[K_IN / 4];
        {
            const float4* wr = reinterpret_cast<const float4*>(W_ih + (size_t)gr * K_IN);
            #pragma unroll
            for (int k = 0; k < K_IN / 4; ++k) wih4[k] = wr[k];
        }
        __syncthreads();   // xstage ready (prev chunk fully done)

        // ---- Chunk GEMM: xg_s[tm][tid] = bias + dot(W_ih[gr], x[t]) ----
        for (int tm = 0; tm < CH; ++tm) {
            const float4* xp = reinterpret_cast<const float4*>(xstage + tm * K_IN);
            float a0 = bias, a1 = 0.0f, a2 = 0.0f, a3 = 0.0f;
            #pragma unroll
            for (int k = 0; k < K_IN / 4; ++k) {
                float4 v = xp[k];                 // broadcast b128 (conflict-free)
                a0 = fmaf(wih4[k].x, v.x, a0);
                a1 = fmaf(wih4[k].y, v.y, a1);
                a2 = fmaf(wih4[k].z, v.z, a2);
                a3 = fmaf(wih4[k].w, v.w, a3);
            }
            xg_s[tm * NGATES + tid] = (a0 + a1) + (a2 + a3);  // lane-stride-1
        }
        __syncthreads();   // xg_s ready

        // ---- Serial recurrence: one barrier per step ----
        for (int tm = 0; tm < CH; ++tm) {
            const int t = c0 + tm;
            const int p = t & 1;
            const float4* hb4 = reinterpret_cast<const float4*>(hbuf[p]);

            float a0 = xg_s[tm * NGATES + tid], a1 = 0.0f, a2 = 0.0f, a3 = 0.0f;
            #pragma unroll
            for (int k = 0; k < HID / 4; ++k) {
                float4 hv = hb4[k];               // broadcast b128
                a0 = fmaf(whh4[k].x, hv.x, a0);
                a1 = fmaf(whh4[k].y, hv.y, a1);
                a2 = fmaf(whh4[k].z, hv.z, a2);
                a3 = fmaf(whh4[k].w, hv.w, a3);
            }
            const float acc = (a0 + a1) + (a2 + a3);
            const float act = sB + sC / (1.0f + __expf(sA * acc));

            // Gather the 4 gates of unit u into the gid==0 lane (intra-wave).
            const float s1 = __shfl_xor(act, 16);   // partner gate gid^1
            const float s2 = __shfl_xor(act, 32);   // gid^2
            const float s3 = __shfl_xor(s1, 32);    // gid^3
            if (gid == 0) {
                // act=i, s1=f, s2=g, s3=o
                c = fmaf(s1, c, act * s2);
                const float h = s3 * fast_tanh(c);
                hbuf[p ^ 1][u] = h;                 // 16 lanes/wave, distinct banks
                if (!LAST) hout[((size_t)b * T_STEPS + t) * HID + u] = h;
            }
            __syncthreads();   // h(t) visible; also guards hbuf WAR + xg_s WAR
        }
    }

    if (LAST) {
        // Final h is in hbuf[0] (last step t=511 wrote parity 1^1=0).
        if (tid < HID) {
            float v = hbuf[0][tid] * W_fc[tid];
            #pragma unroll
            for (int off = 32; off; off >>= 1) v += __shfl_down(v, off);
            if (tid == 0) fcout[b] = v + b_fc[0];
        }
    }
}

extern "C" void kernel_launch(void* const* d_in, const int* in_sizes, int n_in,
                              void* d_out, int out_size, void* d_ws, size_t ws_size,
                              hipStream_t stream) {
    const float* x     = (const float*)d_in[0];
    const float* W_ih0 = (const float*)d_in[1];
    const float* W_hh0 = (const float*)d_in[2];
    const float* b_ih0 = (const float*)d_in[3];
    const float* b_hh0 = (const float*)d_in[4];
    const float* W_ih1 = (const float*)d_in[5];
    const float* W_hh1 = (const float*)d_in[6];
    const float* b_ih1 = (const float*)d_in[7];
    const float* b_hh1 = (const float*)d_in[8];
    const float* W_fc  = (const float*)d_in[9];
    const float* b_fc  = (const float*)d_in[10];

    float* out = (float*)d_out;
    float* h1  = (float*)d_ws;   // [512,512,64] f32 = 64 MB scratch

    lstm_layer<32, false><<<BATCH, 256, 0, stream>>>(
        x, W_ih0, W_hh0, b_ih0, b_hh0, h1, nullptr, nullptr, nullptr);
    lstm_layer<64, true><<<BATCH, 256, 0, stream>>>(
        h1, W_ih1, W_hh1, b_ih1, b_hh1, nullptr, W_fc, b_fc, out);
}